// Round 1
// baseline (44.569 us; speedup 1.0000x reference)
//
#include <hip/hip_runtime.h>

#define NPIX  65536
#define NG    512
#define NB    4
#define MAXD  362.03867196751236f

__device__ __forceinline__ float wave_sum(float v){
  #pragma unroll
  for (int o = 32; o > 0; o >>= 1) v += __shfl_down(v, o, 64);
  return v;
}
__device__ __forceinline__ float wave_min(float v){
  #pragma unroll
  for (int o = 32; o > 0; o >>= 1) v = fminf(v, __shfl_down(v, o, 64));
  return v;
}

// ws layout (floats):
//   [0,   256)  : per-block partial sum of p*min_d   ([B][64])
//   [256, 512)  : per-block partial sum of p         ([B][64])
//   [512, 2560) : per-(b,g) min of p*(d - MAXD)      ([B][512])

// ---------- term 1: per-pixel nearest-gt distance, prob-weighted ----------
// grid = NB*64 blocks, 256 threads; each thread owns 4 consecutive pixels (same row)
__global__ __launch_bounds__(256) void k_term1(const float* __restrict__ prob,
                                               const int* __restrict__ gt,
                                               float* __restrict__ ws){
  __shared__ float4 gsh[NG];
  __shared__ float red[8];
  const int tid = threadIdx.x;
  const int b   = blockIdx.x >> 6;
  const int blk = blockIdx.x & 63;

  // stage gt as (a=-2*gh, b=-2*gw, c=gh^2+gw^2, 0)
  for (int g = tid; g < NG; g += 256){
    const int gh = gt[(b*NG + g)*2 + 0];
    const int gw = gt[(b*NG + g)*2 + 1];
    const float ghf = (float)gh, gwf = (float)gw;
    gsh[g] = make_float4(-2.0f*ghf, -2.0f*gwf, fmaf(ghf, ghf, gwf*gwf), 0.0f);
  }
  __syncthreads();

  const int base = blk*1024 + tid*4;      // 4 consecutive pixels, same row
  const int h  = base >> 8;
  const int w0 = base & 255;
  const float hf  = (float)h;
  const float wf0 = (float)w0, wf1 = wf0+1.0f, wf2 = wf0+2.0f, wf3 = wf0+3.0f;

  float m0 = 3e38f, m1 = 3e38f, m2 = 3e38f, m3 = 3e38f;
  #pragma unroll 8
  for (int g = 0; g < NG; ++g){
    const float4 q = gsh[g];
    const float t = fmaf(q.x, hf, q.z);            // c - 2*gh*h
    m0 = fminf(m0, fmaf(q.y, wf0, t));             // d2 - (h^2+w^2), exact int
    m1 = fminf(m1, fmaf(q.y, wf1, t));
    m2 = fminf(m2, fmaf(q.y, wf2, t));
    m3 = fminf(m3, fmaf(q.y, wf3, t));
  }

  const float4 p = *reinterpret_cast<const float4*>(prob + b*NPIX + base);
  const float s0 = (float)(h*h + (w0+0)*(w0+0));
  const float s1 = (float)(h*h + (w0+1)*(w0+1));
  const float s2 = (float)(h*h + (w0+2)*(w0+2));
  const float s3 = (float)(h*h + (w0+3)*(w0+3));
  const float d0 = __builtin_amdgcn_sqrtf(m0 + s0);
  const float d1 = __builtin_amdgcn_sqrtf(m1 + s1);
  const float d2 = __builtin_amdgcn_sqrtf(m2 + s2);
  const float d3 = __builtin_amdgcn_sqrtf(m3 + s3);

  float spd = fmaf(p.x, d0, fmaf(p.y, d1, fmaf(p.z, d2, p.w*d3)));
  float sp  = (p.x + p.y) + (p.z + p.w);

  spd = wave_sum(spd);
  sp  = wave_sum(sp);
  const int wid = tid >> 6, lane = tid & 63;
  if (lane == 0){ red[wid] = spd; red[4+wid] = sp; }
  __syncthreads();
  if (tid == 0){
    const float a  = (red[0]+red[1]) + (red[2]+red[3]);
    const float bb = (red[4]+red[5]) + (red[6]+red[7]);
    ws[blockIdx.x]       = a;
    ws[256 + blockIdx.x] = bb;
  }
}

// ---------- term 2: per-gt min over pixels of p*(d - MAXD) ----------
// grid = NB*128 blocks, 256 threads; each block owns 4 gt points, scans all pixels.
// thread's w is fixed (= tid); h advances with loop index.
__global__ __launch_bounds__(256) void k_term2(const float* __restrict__ prob,
                                               const int* __restrict__ gt,
                                               float* __restrict__ ws){
  const int tid = threadIdx.x;
  const int b   = blockIdx.x >> 7;
  const int g0  = (blockIdx.x & 127) * 4;

  const float wf  = (float)tid;
  float aa[4], bc[4];
  #pragma unroll
  for (int j = 0; j < 4; ++j){
    const int gh = gt[(b*NG + g0 + j)*2 + 0];
    const int gw = gt[(b*NG + g0 + j)*2 + 1];
    const float ghf = (float)gh, gwf = (float)gw;
    aa[j] = -2.0f*ghf;
    bc[j] = fmaf(-2.0f*gwf, wf, fmaf(ghf, ghf, gwf*gwf)); // c - 2*gw*w (exact)
  }
  const float wsq = wf*wf;

  float qm0 = 3e38f, qm1 = 3e38f, qm2 = 3e38f, qm3 = 3e38f;
  const float* pr = prob + b*NPIX + tid;
  #pragma unroll 4
  for (int i = 0; i < 256; ++i){
    const float p    = pr[i*256];
    const float hf   = (float)i;
    const float s    = fmaf(hf, hf, wsq);
    const float npmd = p * (-MAXD);
    float d2, d;
    d2 = fmaf(aa[0], hf, s + bc[0]); d = __builtin_amdgcn_sqrtf(d2);
    qm0 = fminf(qm0, fmaf(p, d, npmd));
    d2 = fmaf(aa[1], hf, s + bc[1]); d = __builtin_amdgcn_sqrtf(d2);
    qm1 = fminf(qm1, fmaf(p, d, npmd));
    d2 = fmaf(aa[2], hf, s + bc[2]); d = __builtin_amdgcn_sqrtf(d2);
    qm2 = fminf(qm2, fmaf(p, d, npmd));
    d2 = fmaf(aa[3], hf, s + bc[3]); d = __builtin_amdgcn_sqrtf(d2);
    qm3 = fminf(qm3, fmaf(p, d, npmd));
  }

  qm0 = wave_min(qm0); qm1 = wave_min(qm1);
  qm2 = wave_min(qm2); qm3 = wave_min(qm3);
  __shared__ float red[4][4];
  const int wid = tid >> 6, lane = tid & 63;
  if (lane == 0){ red[wid][0]=qm0; red[wid][1]=qm1; red[wid][2]=qm2; red[wid][3]=qm3; }
  __syncthreads();
  if (tid == 0){
    #pragma unroll
    for (int j = 0; j < 4; ++j){
      const float v = fminf(fminf(red[0][j], red[1][j]), fminf(red[2][j], red[3][j]));
      ws[512 + blockIdx.x*4 + j] = v;
    }
  }
}

// ---------- finish: deterministic reduction to scalar ----------
__global__ __launch_bounds__(256) void k_finish(const float* __restrict__ ws,
                                                float* __restrict__ out){
  const int tid = threadIdx.x;
  __shared__ float red[4];
  __shared__ float t1[NB];

  // sum the 2048 term-2 mins
  float s = 0.0f;
  #pragma unroll
  for (int k = 0; k < 8; ++k) s += ws[512 + tid + 256*k];
  s = wave_sum(s);
  const int wid = tid >> 6, lane = tid & 63;
  if (lane == 0) red[wid] = s;
  __syncthreads();

  if (tid < NB){
    float pd = 0.0f, pp = 0.0f;
    for (int k = 0; k < 64; ++k){
      pd += ws[tid*64 + k];
      pp += ws[256 + tid*64 + k];
    }
    t1[tid] = pd / (pp + 1e-6f);
  }
  __syncthreads();

  if (tid == 0){
    const float s2    = (red[0]+red[1]) + (red[2]+red[3]);
    const float term2 = MAXD + s2 * (1.0f/2048.0f);
    const float term1 = ((t1[0]+t1[1]) + (t1[2]+t1[3])) * 0.25f;
    out[0] = term1 + term2;
  }
}

extern "C" void kernel_launch(void* const* d_in, const int* in_sizes, int n_in,
                              void* d_out, int out_size, void* d_ws, size_t ws_size,
                              hipStream_t stream) {
  const float* prob = (const float*)d_in[0];
  const int*   gt   = (const int*)d_in[1];
  float* out = (float*)d_out;
  float* ws  = (float*)d_ws;

  hipLaunchKernelGGL(k_term1,  dim3(NB*64),  dim3(256), 0, stream, prob, gt, ws);
  hipLaunchKernelGGL(k_term2,  dim3(NB*128), dim3(256), 0, stream, prob, gt, ws);
  hipLaunchKernelGGL(k_finish, dim3(1),      dim3(256), 0, stream, ws, out);
}

// Round 2
// 42.319 us; speedup vs baseline: 1.0532x; 1.0532x over previous
//
#include <hip/hip_runtime.h>

#define NPIX  65536
#define NG    512
#define NB    4
#define MAXD  362.03867196751236f
#define WRAD  24                  // Chebyshev window radius for phase 1
#define WDIM  49                  // 2*WRAD+1
#define WCNT  2401                // WDIM*WDIM
#define SAFE_Q (23.0f - MAXD)     // q <= this  =>  window provably contains the min

// ws layout (floats):
//   [0,   256)      : per-block partial sum of p*min_d   ([B][64])   (k_main term1)
//   [256, 512)      : per-block partial sum of p         ([B][64])   (k_main term1)
//   [512, 2560)     : per-(b,g) min of p*(d - MAXD)      ([B][512])  (k_phase1, k_main fallback)
//   [4096, 12288)   : gabc float4 per (b,g): (-2gh, -2gw, gh^2+gw^2, 0)

__device__ __forceinline__ float wave_sum(float v){
  #pragma unroll
  for (int o = 32; o > 0; o >>= 1) v += __shfl_down(v, o, 64);
  return v;
}
__device__ __forceinline__ float wave_min(float v){
  #pragma unroll
  for (int o = 32; o > 0; o >>= 1) v = fminf(v, __shfl_down(v, o, 64));
  return v;
}

// ---------- phase 1: windowed term-2 min + gabc prep ----------
// grid = NB*NG blocks, 256 threads; block handles one (b,g).
__global__ __launch_bounds__(256) void k_phase1(const float* __restrict__ prob,
                                                const int* __restrict__ gt,
                                                float* __restrict__ ws){
  const int tid = threadIdx.x;
  const int idx = blockIdx.x;            // b*NG + g
  const int b   = idx >> 9;
  const int gh  = gt[idx*2 + 0];
  const int gw  = gt[idx*2 + 1];

  if (tid == 0){
    const float ghf = (float)gh, gwf = (float)gw;
    float4* gabc = (float4*)(ws + 4096);
    gabc[idx] = make_float4(-2.0f*ghf, -2.0f*gwf, fmaf(ghf, ghf, gwf*gwf), 0.0f);
  }

  float qm = 3e38f;
  for (int i = tid; i < WCNT; i += 256){
    const int r  = i / WDIM;             // const-divide -> magic mul
    const int c  = i - r*WDIM;
    const int hh = gh - WRAD + r;
    const int ww = gw - WRAD + c;
    if ((unsigned)hh < 256u && (unsigned)ww < 256u){
      const float p   = prob[b*NPIX + hh*256 + ww];
      const int   dh  = r - WRAD, dw = c - WRAD;
      const float d2  = (float)(dh*dh + dw*dw);       // exact int in fp32
      const float d   = __builtin_amdgcn_sqrtf(d2);
      const float npmd = p * (-MAXD);
      qm = fminf(qm, fmaf(p, d, npmd));
    }
  }

  qm = wave_min(qm);
  __shared__ float red[4];
  const int wid = tid >> 6, lane = tid & 63;
  if (lane == 0) red[wid] = qm;
  __syncthreads();
  if (tid == 0)
    ws[512 + idx] = fminf(fminf(red[0], red[1]), fminf(red[2], red[3]));
}

// ---------- main: term-1 full scan (blocks 0..255) + term-2 fallback (blocks 256..2303) ----------
__global__ __launch_bounds__(256) void k_main(const float* __restrict__ prob,
                                              const int* __restrict__ gt,
                                              float* __restrict__ ws){
  const int tid = threadIdx.x;

  if (blockIdx.x < 256){
    // ----- term 1: each thread owns 4 consecutive pixels (same row) -----
    const int b   = blockIdx.x >> 6;
    const int blk = blockIdx.x & 63;
    const float4* __restrict__ gq = ((const float4*)(ws + 4096)) + b*NG;

    const int base = blk*1024 + tid*4;
    const int h  = base >> 8;
    const int w0 = base & 255;
    const float hf  = (float)h;
    const float wf0 = (float)w0, wf1 = wf0+1.0f, wf2 = wf0+2.0f, wf3 = wf0+3.0f;

    float m0 = 3e38f, m1 = 3e38f, m2 = 3e38f, m3 = 3e38f;
    #pragma unroll 8
    for (int g = 0; g < NG; ++g){
      const float4 q = gq[g];                 // wave-uniform -> s_load_dwordx4
      const float t = fmaf(q.x, hf, q.z);     // c - 2*gh*h
      m0 = fminf(m0, fmaf(q.y, wf0, t));      // d2 - (h^2+w^2), exact int
      m1 = fminf(m1, fmaf(q.y, wf1, t));
      m2 = fminf(m2, fmaf(q.y, wf2, t));
      m3 = fminf(m3, fmaf(q.y, wf3, t));
    }

    const float4 p = *reinterpret_cast<const float4*>(prob + b*NPIX + base);
    const float s0 = (float)(h*h + (w0+0)*(w0+0));
    const float s1 = (float)(h*h + (w0+1)*(w0+1));
    const float s2 = (float)(h*h + (w0+2)*(w0+2));
    const float s3 = (float)(h*h + (w0+3)*(w0+3));
    const float d0 = __builtin_amdgcn_sqrtf(m0 + s0);
    const float d1 = __builtin_amdgcn_sqrtf(m1 + s1);
    const float d2 = __builtin_amdgcn_sqrtf(m2 + s2);
    const float d3 = __builtin_amdgcn_sqrtf(m3 + s3);

    float spd = fmaf(p.x, d0, fmaf(p.y, d1, fmaf(p.z, d2, p.w*d3)));
    float sp  = (p.x + p.y) + (p.z + p.w);

    spd = wave_sum(spd);
    sp  = wave_sum(sp);
    __shared__ float red[8];
    const int wid = tid >> 6, lane = tid & 63;
    if (lane == 0){ red[wid] = spd; red[4+wid] = sp; }
    __syncthreads();
    if (tid == 0){
      ws[blockIdx.x]       = (red[0]+red[1]) + (red[2]+red[3]);
      ws[256 + blockIdx.x] = (red[4]+red[5]) + (red[6]+red[7]);
    }
  } else {
    // ----- term 2 fallback: full rescan of one (b,g) iff window min not provably global -----
    const int idx = blockIdx.x - 256;        // b*NG + g
    if (ws[512 + idx] <= SAFE_Q) return;     // window covered the true min: done

    const int b  = idx >> 9;
    const int gh = gt[idx*2 + 0];
    const int gw = gt[idx*2 + 1];
    const float ghf = (float)gh, gwf = (float)gw;
    const float aa  = -2.0f*ghf;
    const float wf  = (float)tid;
    const float bc  = fmaf(-2.0f*gwf, wf, fmaf(ghf, ghf, gwf*gwf));
    const float wsq = wf*wf;

    float qm = 3e38f;
    const float* pr = prob + b*NPIX + tid;
    #pragma unroll 4
    for (int i = 0; i < 256; ++i){
      const float p    = pr[i*256];
      const float hf   = (float)i;
      const float s    = fmaf(hf, hf, wsq);
      const float d2v  = fmaf(aa, hf, s + bc);
      const float d    = __builtin_amdgcn_sqrtf(d2v);
      const float npmd = p * (-MAXD);
      qm = fminf(qm, fmaf(p, d, npmd));
    }
    qm = wave_min(qm);
    __shared__ float red2[4];
    const int wid = tid >> 6, lane = tid & 63;
    if (lane == 0) red2[wid] = qm;
    __syncthreads();
    if (tid == 0)
      ws[512 + idx] = fminf(fminf(red2[0], red2[1]), fminf(red2[2], red2[3]));
  }
}

// ---------- finish: deterministic reduction to scalar ----------
__global__ __launch_bounds__(256) void k_finish(const float* __restrict__ ws,
                                                float* __restrict__ out){
  const int tid = threadIdx.x;
  __shared__ float red[4];
  __shared__ float t1[NB];

  float s = 0.0f;
  #pragma unroll
  for (int k = 0; k < 8; ++k) s += ws[512 + tid + 256*k];
  s = wave_sum(s);
  const int wid = tid >> 6, lane = tid & 63;
  if (lane == 0) red[wid] = s;
  __syncthreads();

  if (tid < NB){
    float pd = 0.0f, pp = 0.0f;
    for (int k = 0; k < 64; ++k){
      pd += ws[tid*64 + k];
      pp += ws[256 + tid*64 + k];
    }
    t1[tid] = pd / (pp + 1e-6f);
  }
  __syncthreads();

  if (tid == 0){
    const float s2    = (red[0]+red[1]) + (red[2]+red[3]);
    const float term2 = MAXD + s2 * (1.0f/2048.0f);
    const float term1 = ((t1[0]+t1[1]) + (t1[2]+t1[3])) * 0.25f;
    out[0] = term1 + term2;
  }
}

extern "C" void kernel_launch(void* const* d_in, const int* in_sizes, int n_in,
                              void* d_out, int out_size, void* d_ws, size_t ws_size,
                              hipStream_t stream) {
  const float* prob = (const float*)d_in[0];
  const int*   gt   = (const int*)d_in[1];
  float* out = (float*)d_out;
  float* ws  = (float*)d_ws;

  hipLaunchKernelGGL(k_phase1, dim3(NB*NG),     dim3(256), 0, stream, prob, gt, ws);
  hipLaunchKernelGGL(k_main,   dim3(256 + NB*NG), dim3(256), 0, stream, prob, gt, ws);
  hipLaunchKernelGGL(k_finish, dim3(1),         dim3(256), 0, stream, ws, out);
}